// Round 4
// baseline (91.783 us; speedup 1.0000x reference)
//
#include <hip/hip_runtime.h>

#define NB     32
#define NATOM  48
#define NGRID  128
#define KT     8                          /* grid points per block */
#define NTHR   192                        /* 3 waves */

#define MBTR_ELEMS (NB*16*NGRID)          /* 65536 */
#define DIV_PER_B  (16*NGRID*NATOM*3)     /* 294912 */
#define PANE       (NGRID*NATOM*3)        /* 18432 floats per (e1,e2) pane */
#define FSTRIDE    49                     /* padded n-stride per field */
#define KSTRIDE    (16*FSTRIDE)           /* 784 floats per k slab */

// Fused MBTR fwd+div, 2-k-per-thread phase 1.
// Phase 1: thread = (n, kq in 0..3) accumulates grid points k0+kq and
// k0+kq+4; pair geometry (diff, d2, rsq, scalings) computed ONCE per m and
// shared by both k's. coef is folded into the exp2 argument, so per-k work
// is 8 VALU + one exp2. Self-pair killed via base=1e30 (exp2 -> 0).
// Phase 2: R2/R3-verified coalesced float4 expansion into (E,E,G,N,3).
__global__ __launch_bounds__(NTHR)
void mbtr_fused(const float* __restrict__ r, const int* __restrict__ z,
                const float* __restrict__ grid, float* __restrict__ out)
{
    const int kt = blockIdx.x, b = blockIdx.y, t = threadIdx.x;
    const int k0 = kt * KT;

    __shared__ float4 pos[NATOM];
    __shared__ int    zl[NATOM];
    __shared__ int    order[NATOM];
    __shared__ float  Arec[KT * KSTRIDE];   /* [kk][f][49]; [.][.][48] = 0 */

    // ---- setup: wave 0 loads atoms and builds the species-sorted order ----
    if (t < 64) {
        const bool isatom = (t < NATOM);
        int myz = 999;
        if (isatom) {
            myz = z[t];
            zl[t] = myz;
            const float* rp = r + ((size_t)b * NATOM + t) * 3;
            pos[t] = make_float4(rp[0], rp[1], rp[2], 0.f);
        }
        const unsigned long long m0 = __ballot(myz == 0);
        const unsigned long long m1 = __ballot(myz == 1);
        const unsigned long long m2 = __ballot(myz == 2);
        const unsigned long long m3 = __ballot(myz == 3);
        const int c0 = __popcll(m0), c1 = __popcll(m1), c2 = __popcll(m2);
        if (isatom) {
            const unsigned long long mm = (myz == 0) ? m0 : (myz == 1) ? m1
                                        : (myz == 2) ? m2 : m3;
            const int base = (myz == 0) ? 0 : (myz == 1) ? c0
                           : (myz == 2) ? c0 + c1 : c0 + c1 + c2;
            const int rank = __popcll(mm & ((1ull << t) - 1ull));
            order[base + rank] = t;
        }
    }
    if (t < KT * 16)   // zero dummy column 48 of every [kk][f] row
        Arec[(t >> 4) * KSTRIDE + (t & 15) * FSTRIDE + NATOM] = 0.f;
    __syncthreads();

    // ---- phase 1: thread = (n, kq), two grid points per thread ----
    const int n  = t % NATOM;
    const int kq = t / NATOM;               // 0..3
    const float dx   = grid[1] - grid[0];
    const float coef = dx * 7.9788456080286535f;     // dx*20/sqrt(2pi)
    const float mlc  = -__log2f(coef);
    const float isc  = 16.986436005760382f;          // 20*sqrt(log2e/2)
    const float tBc  = 23.548200452219559f;          // 20/sqrt(log2e/2)
    const float l2e  = 1.4426950408889634f;
    const float gkA  = grid[k0 + kq]     * isc;
    const float gkB  = grid[k0 + kq + 4] * isc;

    float A[2][4][3] = {{{0.f}}};
    float M[2][4]    = {{0.f}};
    const float4 rn = pos[n];

    // species-run bounds from zl counts (uniform, recomputed cheaply)
    int so[5];
    {
        int cnt0 = 0, cnt1 = 0, cnt2 = 0;
        // counts are wave-uniform; derive from the sorted order array bounds
        // via zl of order entries would need LDS reads; instead recount from
        // ballot-free method: read zl serially is 48 LDS reads -- avoid by
        // storing counts in order[]? Simpler: scan species of sorted order
        // lazily inside the loop (e advances when species changes).
        (void)cnt0; (void)cnt1; (void)cnt2;
        so[0] = 0; so[4] = NATOM;
    }

    // single 48-iteration loop; species id read per m (broadcast LDS)
    #pragma unroll 4
    for (int i = 0; i < NATOM; ++i) {
        const int    m  = order[i];            // uniform -> broadcast
        const int    e  = zl[m];               // uniform -> broadcast
        const float4 rm = pos[m];              // uniform -> broadcast
        const float ddx = rn.x - rm.x, ddy = rn.y - rm.y, ddz = rn.z - rm.z;
        float d2 = ddx*ddx + ddy*ddy + ddz*ddz;
        const bool self = (m == n);
        d2 = self ? 1.0f : d2;                        // rsq NaN guard
        const float gf  = __builtin_amdgcn_rsqf(d2);  // 1/d
        const float c1  = gf * isc;
        const float d   = d2 * gf;
        float base = fmaf(d, l2e, mlc);               // wf & coef folded
        base = self ? 1e30f : base;                   // kill self pair
        const float bq  = (gf * gf) * tBc;
        const float sux = gf * ddx, suy = gf * ddy, suz = gf * ddz;
        {   // k = k0 + kq
            const float tt = gkA - c1;
            const float ex = exp2f(-fmaf(tt, tt, base));   // wf*gv*coef
            M[0][e] += ex;
            const float p  = ex * fmaf(tt, bq, 1.0f);
            A[0][e][0] = fmaf(-p, sux, A[0][e][0]);
            A[0][e][1] = fmaf(-p, suy, A[0][e][1]);
            A[0][e][2] = fmaf(-p, suz, A[0][e][2]);
        }
        {   // k = k0 + kq + 4
            const float tt = gkB - c1;
            const float ex = exp2f(-fmaf(tt, tt, base));
            M[1][e] += ex;
            const float p  = ex * fmaf(tt, bq, 1.0f);
            A[1][e][0] = fmaf(-p, sux, A[1][e][0]);
            A[1][e][1] = fmaf(-p, suy, A[1][e][1]);
            A[1][e][2] = fmaf(-p, suz, A[1][e][2]);
        }
    }
    (void)so;

    {   // store both k slabs: field-major stripes, bank ~ n mod 32
        float* ar0 = Arec + kq       * KSTRIDE + n;
        float* ar1 = Arec + (kq + 4) * KSTRIDE + n;
        #pragma unroll
        for (int e = 0; e < 4; ++e) {
            ar0[(e * 3 + 0) * FSTRIDE] = A[0][e][0];
            ar0[(e * 3 + 1) * FSTRIDE] = A[0][e][1];
            ar0[(e * 3 + 2) * FSTRIDE] = A[0][e][2];
            ar0[(12 + e)    * FSTRIDE] = M[0][e];
            ar1[(e * 3 + 0) * FSTRIDE] = A[1][e][0];
            ar1[(e * 3 + 1) * FSTRIDE] = A[1][e][1];
            ar1[(e * 3 + 2) * FSTRIDE] = A[1][e][2];
            ar1[(12 + e)    * FSTRIDE] = M[1][e];
        }
    }
    __syncthreads();

    // ---- phase 2: coalesced expansion -> out (576 float4 per k = 192*3) --
    int a1[3][4], a2[3][4], obase[3];
    #pragma unroll
    for (int jj = 0; jj < 3; ++jj) {
        const int u = t + NTHR * jj;           // 0..575, exact cover
        const int pane = u / 36, w36 = u % 36;
        const int e1 = pane >> 2, e2 = pane & 3;
        obase[jj] = pane * PANE + w36 * 4;
        #pragma unroll
        for (int s = 0; s < 4; ++s) {
            const int p = w36 * 4 + s, nn = p / 3, c = p - nn * 3;
            a1[jj][s] = (zl[nn] == e1) ? ((e2 * 3 + c) * FSTRIDE + nn)
                                       : ((e2 * 3 + c) * FSTRIDE + NATOM);
            a2[jj][s] = (zl[nn] == e2) ? ((e1 * 3 + c) * FSTRIDE + nn)
                                       : ((e1 * 3 + c) * FSTRIDE + NATOM);
        }
    }

    float* divout = out + MBTR_ELEMS + (size_t)b * DIV_PER_B;
    #pragma unroll
    for (int kk = 0; kk < KT; ++kk) {
        const float* trk = Arec + kk * KSTRIDE;
        const int k = k0 + kk;
        #pragma unroll
        for (int jj = 0; jj < 3; ++jj) {
            float4 v;
            v.x = trk[a1[jj][0]] + trk[a2[jj][0]];
            v.y = trk[a1[jj][1]] + trk[a2[jj][1]];
            v.z = trk[a1[jj][2]] + trk[a2[jj][2]];
            v.w = trk[a1[jj][3]] + trk[a2[jj][3]];
            *(float4*)(divout + obase[jj] + k * 144) = v;
        }
    }

    if (t < 128) {   // mbtr: one (pane, kk) sum per thread
        const int mpane = t >> 3, mkk = t & 7;
        const int me1 = mpane >> 2, me2 = mpane & 3;
        const float* tr2 = Arec + mkk * KSTRIDE + (12 + me2) * FSTRIDE;
        float s = 0.f;
        #pragma unroll
        for (int nn = 0; nn < NATOM; ++nn)
            s += (zl[nn] == me1) ? tr2[nn] : 0.f;
        out[(size_t)b * 2048 + mpane * NGRID + k0 + mkk] = s;
    }
}

extern "C" void kernel_launch(void* const* d_in, const int* in_sizes, int n_in,
                              void* d_out, int out_size, void* d_ws, size_t ws_size,
                              hipStream_t stream)
{
    const float* r    = (const float*)d_in[0];
    const int*   z    = (const int*)  d_in[1];
    const float* grid = (const float*)d_in[2];
    float* out = (float*)d_out;
    (void)d_ws; (void)ws_size;

    mbtr_fused<<<dim3(NGRID / KT, NB), NTHR, 0, stream>>>(r, z, grid, out);
}

// Round 5
// 80.751 us; speedup vs baseline: 1.1366x; 1.1366x over previous
//
#include <hip/hip_runtime.h>

#define NB     32
#define NATOM  48
#define NGRID  128
#define KT     8                          /* grid points per block */
#define NTHR   384                        /* 6 waves: thread = (n, kk) */

#define MBTR_ELEMS (NB*16*NGRID)          /* 65536 */
#define DIV_PER_B  (16*NGRID*NATOM*3)     /* 294912 */
#define PANE       (NGRID*NATOM*3)        /* 18432 floats per (e1,e2) pane */
#define MSTRIDE    49                     /* padded n-stride for M table */

// Fused MBTR fwd+div, register-direct output.
// Phase 1: thread = (n, kk) accumulates A_n[e][c] = sum_{m:z[m]=e} s*u_c and
// M_n[e] = sum wf*gv for grid point k0+kk, via the species-SEGMENTED loop
// (e static after unroll -> A stays in registers; R4's runtime-e indexing
// forced cndmask/scratch and regressed 9us). wf and coef folded into the
// exp2 argument; self-pair killed via base=1e30.
// Phase 2: each thread writes its own 48 div floats STRAIGHT FROM REGISTERS
// (pane value is a 2-term cndmask select over A) -- no Arec LDS round-trip.
// Only the 6.3 KB M table goes through LDS for the mbtr reduction.
__global__ __launch_bounds__(NTHR)
void mbtr_fused(const float* __restrict__ r, const int* __restrict__ z,
                const float* __restrict__ grid, float* __restrict__ out)
{
    const int kt = blockIdx.x, b = blockIdx.y, t = threadIdx.x;
    const int k0 = kt * KT;

    __shared__ float4 pos[NATOM];
    __shared__ int    zl[NATOM];
    __shared__ int    order[NATOM];
    __shared__ int    soff_s[5];
    __shared__ float  Mrec[KT * 4 * MSTRIDE];   /* [kk][e][49] */

    // ---- setup: wave 0 loads atoms, builds species-sorted order ----
    if (t < 64) {
        const bool isatom = (t < NATOM);
        int myz = 999;
        if (isatom) {
            myz = z[t];
            zl[t] = myz;
            const float* rp = r + ((size_t)b * NATOM + t) * 3;
            pos[t] = make_float4(rp[0], rp[1], rp[2], 0.f);
        }
        const unsigned long long m0 = __ballot(myz == 0);
        const unsigned long long m1 = __ballot(myz == 1);
        const unsigned long long m2 = __ballot(myz == 2);
        const unsigned long long m3 = __ballot(myz == 3);
        const int c0 = __popcll(m0), c1 = __popcll(m1), c2 = __popcll(m2);
        if (isatom) {
            const unsigned long long mm = (myz == 0) ? m0 : (myz == 1) ? m1
                                        : (myz == 2) ? m2 : m3;
            const int base = (myz == 0) ? 0 : (myz == 1) ? c0
                           : (myz == 2) ? c0 + c1 : c0 + c1 + c2;
            const int rank = __popcll(mm & ((1ull << t) - 1ull));
            order[base + rank] = t;
        }
        if (t == 0) {
            soff_s[0] = 0; soff_s[1] = c0; soff_s[2] = c0 + c1;
            soff_s[3] = c0 + c1 + c2; soff_s[4] = NATOM;
        }
    }
    __syncthreads();

    // ---- phase 1: thread = (n, kk), one grid point ----
    const int n  = t % NATOM;
    const int kk = t / NATOM;               // 0..7
    const float dx   = grid[1] - grid[0];
    const float coef = dx * 7.9788456080286535f;     // dx*20/sqrt(2pi)
    const float mlc  = -__log2f(coef);
    const float isc  = 16.986436005760382f;          // 20*sqrt(log2e/2)
    const float tBc  = 23.548200452219559f;          // 20/sqrt(log2e/2)
    const float l2e  = 1.4426950408889634f;
    const float gk   = grid[k0 + kk] * isc;

    float A[4][3] = {{0.f}};
    float M[4]    = {0.f};
    const float4 rn = pos[n];
    const int   zn  = zl[n];
    int so[5];
    #pragma unroll
    for (int e = 0; e < 5; ++e) so[e] = soff_s[e];

    #pragma unroll
    for (int e = 0; e < 4; ++e) {           // e STATIC -> A[e] in registers
        for (int i = so[e]; i < so[e + 1]; ++i) {
            const int    m  = order[i];     // uniform -> broadcast
            const float4 rm = pos[m];       // uniform -> broadcast
            const float ddx = rn.x - rm.x, ddy = rn.y - rm.y, ddz = rn.z - rm.z;
            float d2 = ddx*ddx + ddy*ddy + ddz*ddz;
            const bool self = (m == n);
            d2 = self ? 1.0f : d2;                        // rsq NaN guard
            const float gf  = __builtin_amdgcn_rsqf(d2);  // 1/d
            const float c1  = gf * isc;
            const float d   = d2 * gf;
            float base = fmaf(d, l2e, mlc);               // wf & coef folded
            base = self ? 1e30f : base;                   // kill self pair
            const float bq  = (gf * gf) * tBc;
            const float tt  = gk - c1;
            const float ex  = exp2f(-fmaf(tt, tt, base)); // coef*wf*gv
            M[e] += ex;
            const float p   = ex * fmaf(tt, bq, 1.0f);
            A[e][0] = fmaf(-p, gf * ddx, A[e][0]);
            A[e][1] = fmaf(-p, gf * ddy, A[e][1]);
            A[e][2] = fmaf(-p, gf * ddz, A[e][2]);
        }
    }

    {   // M table to LDS (banks spread: 49-stride, n-contiguous lanes)
        float* mr = Mrec + kk * (4 * MSTRIDE) + n;
        #pragma unroll
        for (int e = 0; e < 4; ++e) mr[e * MSTRIDE] = M[e];
    }

    // ---- phase 2a: div writes straight from registers ----
    // pane (e1,e2) value at (n,c) = (zn==e1)*A[e2][c] + (zn==e2)*A[e1][c]
    float* basep = out + MBTR_ELEMS + (size_t)b * DIV_PER_B
                 + (size_t)(k0 + kk) * 144 + n * 3;
    #pragma unroll
    for (int e1 = 0; e1 < 4; ++e1) {
        const bool s1 = (zn == e1);
        #pragma unroll
        for (int e2 = 0; e2 < 4; ++e2) {
            const bool s2 = (zn == e2);
            float* p = basep + (e1 * 4 + e2) * PANE;
            p[0] = (s1 ? A[e2][0] : 0.f) + (s2 ? A[e1][0] : 0.f);
            p[1] = (s1 ? A[e2][1] : 0.f) + (s2 ? A[e1][1] : 0.f);
            p[2] = (s1 ? A[e2][2] : 0.f) + (s2 ? A[e1][2] : 0.f);
        }
    }

    __syncthreads();

    // ---- phase 2b: mbtr reduction (threads 0..127: one (pane,kk) each) ----
    if (t < 128) {
        const int mpane = t >> 3, mkk = t & 7;
        const int me1 = mpane >> 2, me2 = mpane & 3;
        const float* tr2 = Mrec + mkk * (4 * MSTRIDE) + me2 * MSTRIDE;
        float s = 0.f;
        #pragma unroll
        for (int nn = 0; nn < NATOM; ++nn)
            s += (zl[nn] == me1) ? tr2[nn] : 0.f;
        out[(size_t)b * 2048 + mpane * NGRID + k0 + mkk] = s;
    }
}

extern "C" void kernel_launch(void* const* d_in, const int* in_sizes, int n_in,
                              void* d_out, int out_size, void* d_ws, size_t ws_size,
                              hipStream_t stream)
{
    const float* r    = (const float*)d_in[0];
    const int*   z    = (const int*)  d_in[1];
    const float* grid = (const float*)d_in[2];
    float* out = (float*)d_out;
    (void)d_ws; (void)ws_size;

    mbtr_fused<<<dim3(NGRID / KT, NB), NTHR, 0, stream>>>(r, z, grid, out);
}